// Round 7
// baseline (24.529 us; speedup 1.0000x reference)
//
#include <hip/hip_runtime.h>
#include <math.h>

#define CTX 24
#define DKK 92
#define ED 36
#define NTOK 500
#define HID 152

#define NBLK 19
#define COLS 8            // h-columns per block; NBLK*COLS = 152
#define TOKS 27           // output tokens per block; 19*27 = 513 >= 500
#define POISON 0xAAAAAAAAu

typedef float4 f4;

__device__ __forceinline__ float dot4(f4 a, f4 b) {
    return a.x*b.x + a.y*b.y + a.z*b.z + a.w*b.w;
}

// ---------------------------------------------------------------------------
// Per-attention LDS scratch (one wave owns one instance).
// ---------------------------------------------------------------------------
struct AttnLds {
    f4    xw4[216];   // x0 copy: 36x24 floats = [36][6] f4
    f4    W4[144];    // wq@wk^T: 24x24 = [24][6] f4
    f4    M4[216];    // x0@W:    36x24 = [36][6] f4
    float S[1296];    // scores / probs: 36x36
    float wvs[24];    // rowsum(wv)
    f4    vs24[9];    // vsum[f]/colsum[f], 36 floats
};

// Single-wave self-attention (64 lanes), barrier-free inside a wave
// (wave-lockstep + __threadfence_block between stages). absmax 0.0 R2/R4/R5/R6.
__device__ void attn_wave(int lane, const float* __restrict__ x0,
                          const float* __restrict__ wq, const float* __restrict__ wk,
                          const float* __restrict__ wv,
                          AttnLds& L, float* __restrict__ dst /* 36 out, LDS */)
{
    const f4* x0g = (const f4*)x0;
    for (int i = lane; i < 216; i += 64) L.xw4[i] = x0g[i];
    if (lane < CTX) {
        const f4* wvr = (const f4*)(wv + lane * DKK);
        f4 s = {0.f, 0.f, 0.f, 0.f};
        #pragma unroll
        for (int c = 0; c < 23; ++c) {
            f4 v = wvr[c];
            s.x += v.x; s.y += v.y; s.z += v.z; s.w += v.w;
        }
        L.wvs[lane] = s.x + s.y + s.z + s.w;
    }
    __threadfence_block();

    {   // W[a][b] = sum_d wq[a][d]*wk[b][d]; 8x8 lanes of 3x3 tiles
        const f4* wq4 = (const f4*)wq;
        const f4* wk4 = (const f4*)wk;
        const int a0 = (lane >> 3) * 3, b0 = (lane & 7) * 3;
        float acc[3][3] = {};
        #pragma unroll 4
        for (int dc = 0; dc < 23; ++dc) {
            f4 qa[3], kb[3];
            #pragma unroll
            for (int r = 0; r < 3; ++r) qa[r] = wq4[(a0 + r) * 23 + dc];
            #pragma unroll
            for (int c = 0; c < 3; ++c) kb[c] = wk4[(b0 + c) * 23 + dc];
            #pragma unroll
            for (int r = 0; r < 3; ++r)
                #pragma unroll
                for (int c = 0; c < 3; ++c)
                    acc[r][c] += dot4(qa[r], kb[c]);
        }
        float* Wf = (float*)L.W4;
        #pragma unroll
        for (int r = 0; r < 3; ++r)
            #pragma unroll
            for (int c = 0; c < 3; ++c)
                Wf[(a0 + r) * 24 + b0 + c] = acc[r][c];
    }
    __threadfence_block();

    {   // M[e][b] = sum_a x0[e][a] * W[a][b]
        const float* xf = (const float*)L.xw4;
        for (int t = lane; t < 72; t += 64) {
            const int e0 = (t / 6) * 3, bq = t % 6;
            f4 acc[3] = {};
            #pragma unroll
            for (int a = 0; a < 24; ++a) {
                f4 w = L.W4[a * 6 + bq];
                #pragma unroll
                for (int r = 0; r < 3; ++r) {
                    float x = xf[(e0 + r) * 24 + a];
                    acc[r].x += x * w.x; acc[r].y += x * w.y;
                    acc[r].z += x * w.z; acc[r].w += x * w.w;
                }
            }
            #pragma unroll
            for (int r = 0; r < 3; ++r) L.M4[(e0 + r) * 6 + bq] = acc[r];
        }
    }
    __threadfence_block();

    {   // S[e][f] = sqrt(92) * sum_b M[e][b]*x0[f][b]
        const float scale = 9.59166304662544f;
        for (int t = lane; t < 108; t += 64) {
            const int e0 = (t / 9) * 3, f0 = (t % 9) * 4;
            float acc[3][4] = {};
            #pragma unroll
            for (int bq = 0; bq < 6; ++bq) {
                f4 m[3], x[4];
                #pragma unroll
                for (int r = 0; r < 3; ++r) m[r] = L.M4[(e0 + r) * 6 + bq];
                #pragma unroll
                for (int c = 0; c < 4; ++c) x[c] = L.xw4[(f0 + c) * 6 + bq];
                #pragma unroll
                for (int r = 0; r < 3; ++r)
                    #pragma unroll
                    for (int c = 0; c < 4; ++c)
                        acc[r][c] += dot4(m[r], x[c]);
            }
            #pragma unroll
            for (int r = 0; r < 3; ++r)
                #pragma unroll
                for (int c = 0; c < 4; ++c)
                    L.S[(e0 + r) * 36 + f0 + c] = acc[r][c] * scale;
        }
    }
    __threadfence_block();

    if (lane < ED) {   // column softmax + vs2[f] = vsum[f]/colsum[f]
        const int f = lane;
        float mx = -1e30f;
        #pragma unroll 4
        for (int e = 0; e < ED; ++e) mx = fmaxf(mx, L.S[e * 36 + f]);
        float sum = 0.f;
        #pragma unroll 4
        for (int e = 0; e < ED; ++e) {
            float p = expf(L.S[e * 36 + f] - mx);
            L.S[e * 36 + f] = p;
            sum += p;
        }
        const float* xf = (const float*)L.xw4;
        float vs = 0.f;
        #pragma unroll
        for (int c = 0; c < CTX; ++c) vs += xf[f * 24 + c] * L.wvs[c];
        ((float*)L.vs24)[f] = vs / sum;
    }
    __threadfence_block();

    if (lane < ED) {
        const int e = lane;
        const f4* Srow = (const f4*)&L.S[e * 36];
        float s = 0.f;
        #pragma unroll
        for (int fq = 0; fq < 9; ++fq) s += dot4(Srow[fq], L.vs24[fq]);
        dst[e] = s;
    }
}

// ---------------------------------------------------------------------------
// One fused kernel, 19 blocks x 256 threads, value-poll join (h >= 0, poison
// 0xAAAAAAAA is negative -> safe sentinel; relaxed agent atomics only).
// R7: post-join tail is 100% LDS-resident — nl1, the 72-row nl0 correction,
// biases, AND this block's ctp token-slice are all prefetched during phase 1
// under the attention shadow. After the join: LDS compute + out store only.
// ---------------------------------------------------------------------------
__global__ __launch_bounds__(256) void fused_vpoll3(
    const float* __restrict__ x0,
    const float* __restrict__ wq1, const float* __restrict__ wk1, const float* __restrict__ wv1,
    const float* __restrict__ wq2, const float* __restrict__ wk2, const float* __restrict__ wv2,
    const float* __restrict__ nl0, const float* __restrict__ nl0_bias,
    const float* __restrict__ nl1, const float* __restrict__ ctp, const float* __restrict__ ctp_bias,
    float* __restrict__ ws, float* __restrict__ out)
{
    __shared__ AttnLds A0, A1;
    __shared__ float conc72[72];        // t3 | t13
    __shared__ f4    part4[128][2];     // x0-part partials [thread][8 floats]
    __shared__ float red[16][COLS];     // reduced main partials
    __shared__ float corr_red[16][COLS];// reduced first-72 correction
    __shared__ f4    nl1s4[1368];       // full nl1 [152][36]
    __shared__ f4    corr72b4[144];     // nl0 rows 0..71, own 8 cols: [72][2]
    __shared__ float ctps[ED][TOKS + 1];// ctp slice [36][27] (+1 pad)
    __shared__ float nl0b8[COLS];
    __shared__ float ctpbs[TOKS];
    __shared__ float hsAll[HID];
    __shared__ float t10p[144];
    __shared__ float t10s[ED];
    __shared__ float tp6[TOKS][9];

    const int b   = blockIdx.x;
    const int tid = threadIdx.x;
    const int c0  = b * COLS;           // first h-column owned by this block
    const int n0  = b * TOKS;           // first token owned by this block
    unsigned int* h_bits = (unsigned int*)ws;

    // ---------------- phase 1 (no barrier needed) ----------------
    if (tid < 64) {
        attn_wave(tid, x0, wq1, wk1, wv1, A0, conc72);
    } else if (tid < 128) {
        attn_wave(tid - 64, x0, wq2, wk2, wv2, A1, conc72 + ED);
    } else {
        // x0-part of this block's 8 columns: rows 72..935 of nl0
        const int t2 = tid - 128;       // 0..127
        f4 a0 = {0.f,0.f,0.f,0.f}, a1 = {0.f,0.f,0.f,0.f};
        for (int r = t2; r < 864; r += 128) {
            const float x = x0[r];
            const f4* row = (const f4*)(nl0 + (72 + r) * HID + c0);
            f4 v0 = row[0], v1 = row[1];
            a0.x += x*v0.x; a0.y += x*v0.y; a0.z += x*v0.z; a0.w += x*v0.w;
            a1.x += x*v1.x; a1.y += x*v1.y; a1.z += x*v1.z; a1.w += x*v1.w;
        }
        part4[t2][0] = a0; part4[t2][1] = a1;

        // prefetch ALL tail operands into LDS (overlaps attention long-pole)
        const f4* nl14 = (const f4*)nl1;
        for (int q = t2; q < 1368; q += 128) nl1s4[q] = nl14[q];
        for (int q = t2; q < 144; q += 128) {
            const int i = q >> 1, half = q & 1;
            corr72b4[q] = ((const f4*)(nl0 + i * HID + c0))[half];
        }
        // ctp token-slice: 36 x 27 floats
        for (int q = t2; q < ED * TOKS; q += 128) {
            const int e = q / TOKS, tok = q % TOKS;
            const int n = n0 + tok;
            ctps[e][tok] = (n < NTOK) ? ctp[e * NTOK + n] : 0.f;
        }
        if (t2 < COLS) nl0b8[t2] = nl0_bias[c0 + t2];
        if (t2 < TOKS) {
            const int n = n0 + t2;
            ctpbs[t2] = (n < NTOK) ? ctp_bias[n] : 0.f;
        }
    }
    __syncthreads();

    // ---------------- phase 2: tree-reduce + first-72 correction ----------------
    if (tid < 128) {
        const int c = tid & 7, g = tid >> 3;     // g in 0..15
        const float* pf = (const float*)part4;
        float s = 0.f;
        #pragma unroll
        for (int k = 0; k < 8; ++k) s += pf[(g + 16*k) * 8 + c];
        red[g][c] = s;
    } else {
        const int t3 = tid - 128;
        const int c = t3 & 7, g = t3 >> 3;       // g in 0..15
        const float* cb = (const float*)corr72b4; // [72][8]
        float s = 0.f;
        for (int i = g; i < 72; i += 16)
            s += conc72[i] * cb[i * 8 + c];
        corr_red[g][c] = s;
    }
    __syncthreads();

    // ---------------- phase 3: finish own h columns, publish (relaxed) --------
    if (tid < COLS) {
        float s = 0.f;
        #pragma unroll
        for (int g = 0; g < 16; ++g) s += red[g][tid] + corr_red[g][tid];
        const float h = fmaxf(s, 0.f) + nl0b8[tid];   // >= 0 always
        __hip_atomic_store(&h_bits[c0 + tid], __float_as_uint(h),
                           __ATOMIC_RELAXED, __HIP_MEMORY_SCOPE_AGENT);
    }

    // ---------------- phase 4: value-poll all 152 h words (f4-wide) ----------
    if (tid < 38) {
        unsigned int w[4];
        bool ok;
        do {
            #pragma unroll
            for (int k = 0; k < 4; ++k)
                w[k] = __hip_atomic_load(&h_bits[4 * tid + k],
                                         __ATOMIC_RELAXED, __HIP_MEMORY_SCOPE_AGENT);
            ok = (w[0] != POISON) && (w[1] != POISON) &&
                 (w[2] != POISON) && (w[3] != POISON);
        } while (!ok);
        #pragma unroll
        for (int k = 0; k < 4; ++k)
            hsAll[4 * tid + k] = __uint_as_float(w[k]);
    }
    __syncthreads();

    // ---------------- phase 5: t10 = h @ nl1 (LDS only) ----------------
    if (tid < 144) {
        const int e = tid % 36, jg = tid / 36;
        const float* nf = (const float*)nl1s4;
        float s = 0.f;
        for (int j = jg; j < HID; j += 4) s += hsAll[j] * nf[j * 36 + e];
        t10p[tid] = s;
    }
    __syncthreads();
    if (tid < ED)
        t10s[tid] = t10p[tid] + t10p[36 + tid] + t10p[72 + tid] + t10p[108 + tid];
    __syncthreads();

    // ---------------- phase 6: token slice, 27 tok x 9 e-groups (LDS only) ----
    if (tid < TOKS * 9) {
        const int tok = tid / 9, g = tid % 9;
        const int e0 = g * 4;
        tp6[tok][g] = t10s[e0]     * ctps[e0][tok]
                    + t10s[e0 + 1] * ctps[e0 + 1][tok]
                    + t10s[e0 + 2] * ctps[e0 + 2][tok]
                    + t10s[e0 + 3] * ctps[e0 + 3][tok];
    }
    __syncthreads();
    if (tid < TOKS) {
        const int n = n0 + tid;
        if (n < NTOK) {
            float s = ctpbs[tid];
            #pragma unroll
            for (int g = 0; g < 9; ++g) s += tp6[tid][g];
            out[n] = s;
        }
    }
}

extern "C" void kernel_launch(void* const* d_in, const int* in_sizes, int n_in,
                              void* d_out, int out_size, void* d_ws, size_t ws_size,
                              hipStream_t stream) {
    const float* x0       = (const float*)d_in[0];
    const float* wq1      = (const float*)d_in[1];
    const float* wk1      = (const float*)d_in[2];
    const float* wv1      = (const float*)d_in[3];
    const float* wq2      = (const float*)d_in[4];
    const float* wk2      = (const float*)d_in[5];
    const float* wv2      = (const float*)d_in[6];
    const float* nl0      = (const float*)d_in[7];
    const float* nl0_bias = (const float*)d_in[8];
    const float* nl1      = (const float*)d_in[9];
    const float* ctp      = (const float*)d_in[10];
    const float* ctp_bias = (const float*)d_in[11];

    fused_vpoll3<<<NBLK, 256, 0, stream>>>(x0, wq1, wk1, wv1, wq2, wk2, wv2,
                                           nl0, nl0_bias, nl1, ctp, ctp_bias,
                                           (float*)d_ws, (float*)d_out);
}